// Round 7
// baseline (759.315 us; speedup 1.0000x reference)
//
#include <hip/hip_runtime.h>

// Shapes: imgs(2,16,3,224,224)[shape only], i_features(8,256,56,56) fp32,
// p_motions(2,12,2,112,112) fp32 -> N=24 frames, C=256, H=W=56, k=3.
#define NPIX 3136
#define NN   24
#define CDIM 256

typedef __attribute__((ext_vector_type(8))) short short8v;   // 8 bf16 (A/B frag)
typedef __attribute__((ext_vector_type(4))) float float4v;   // 4 fp32 (C/D frag)

typedef __attribute__((address_space(1))) const void gvoid;
typedef __attribute__((address_space(3))) void lvoid;
static __device__ __forceinline__ void async_copy16(const void* g, void* l) {
    // lane's 16B lands at l + lane*16 (wave-uniform LDS base)
    __builtin_amdgcn_global_load_lds((gvoid*)g, (lvoid*)l, 16, 0, 0);
}

static __device__ __forceinline__ unsigned short f2b(float f) {
    unsigned int u = __float_as_uint(f);
    u = (u + 0x7FFFu + ((u >> 16) & 1u)) >> 16;   // RNE
    return (unsigned short)u;
}
static __device__ __forceinline__ float b2f(unsigned short h) {
    return __uint_as_float(((unsigned int)h) << 16);
}

// counted wait: drains all but the N newest vmem ops of THIS wave.
// sched_barrier(0) after it prevents hipcc hoisting dependent ds_reads
// above the wait (guide rule #18).
#define WAIT_VMCNT(N) do { \
    asm volatile("s_waitcnt vmcnt(" #N ")" ::: "memory"); \
    __builtin_amdgcn_sched_barrier(0); } while (0)
#define BARRIER() do { __builtin_amdgcn_s_barrier(); \
    __builtin_amdgcn_sched_barrier(0); } while (0)

// ---------------- resize(112->56)*scale == avg2x2 * 0.0625 ------------------
__global__ __launch_bounds__(256) void resize_pm_kernel(
    const float* __restrict__ pmo, float* __restrict__ pm)
{
    int idx = blockIdx.x * 256 + threadIdx.x;
    if (idx >= NN * 2 * NPIX) return;
    int x = idx % 56, y = (idx / 56) % 56, nc = idx / NPIX;
    const float* src = pmo + (size_t)nc * 112 * 112 + (size_t)(2 * y) * 112 + 2 * x;
    pm[idx] = (src[0] + src[1] + src[112] + src[113]) * 0.0625f;
}

// ---------------- merged weight packing (6x 3x3 + 1x 1x1) -------------------
// Arrays 0..4 (E2,E3,E4,M1,M2) + 1x1 (DW): 128-co layout:
//   [cb2][ch8][tap][mi8][lane64][8]; co=cb*128+mi*16+(lane&15),
//   ci=ch*32+(lane>>4)*8+j.
// Array 5 (M3, FUSE kernel): OLD 64-co layout:
//   [cb4][ch8][tap9][g4][lane64][8]; co=cb*64+g*16+(lane&15).
__global__ __launch_bounds__(256) void pack_all_kernel(
    const float* __restrict__ s0, const float* __restrict__ s1,
    const float* __restrict__ s2, const float* __restrict__ s3,
    const float* __restrict__ s4, const float* __restrict__ s5,
    const float* __restrict__ sdw, unsigned short* __restrict__ dstbase)
{
    int bx = blockIdx.x;
    if (bx < 6 * 2304) {
        int wi = bx / 2304;
        int d = (bx % 2304) * 256 + threadIdx.x;
        const float* w = (wi == 0) ? s0 : (wi == 1) ? s1 : (wi == 2) ? s2
                       : (wi == 3) ? s3 : (wi == 4) ? s4 : s5;
        int j = d & 7;
        int lane = (d >> 3) & 63;
        int co, ci, tap;
        if (wi == 5) {            // old layout (FUSE conv M3)
            int g = (d >> 9) & 3;
            int e = d >> 11;
            tap = e % 9;
            int f = e / 9;
            int ch = f & 7, cb = f >> 3;
            co = cb * 64 + g * 16 + (lane & 15);
            ci = ch * 32 + (lane >> 4) * 8 + j;
        } else {                  // 128-co layout
            int mi = (d >> 9) & 7;
            int e = d >> 12;
            tap = e % 9;
            int f = e / 9;
            int ch = f & 7, cb = f >> 3;   // cb 0/1
            co = cb * 128 + mi * 16 + (lane & 15);
            ci = ch * 32 + (lane >> 4) * 8 + j;
        }
        dstbase[(size_t)wi * 589824 + d] = f2b(w[((size_t)co * 256 + ci) * 9 + tap]);
    } else {
        int d = (bx - 6 * 2304) * 256 + threadIdx.x;
        int j = d & 7;
        int lane = (d >> 3) & 63;
        int mi = (d >> 9) & 7;
        int e = d >> 12;          // 0..15
        int ch = e & 7, cb = e >> 3;
        int co = cb * 128 + mi * 16 + (lane & 15);
        int ci = ch * 32 + (lane >> 4) * 8 + j;
        dstbase[(size_t)6 * 589824 + d] = f2b(sdw[(size_t)co * 256 + ci]);
    }
}

// ---------------- ew1 conv (Cin=2, K=18) fp32 direct -> bf16 NHWC + relu ----
__global__ __launch_bounds__(256) void ew1_kernel(
    const float* __restrict__ pm, const float* __restrict__ w,   // (256,2,3,3)
    const float* __restrict__ b, unsigned short* __restrict__ out)
{
    __shared__ float sT[8][18];
    __shared__ float sW1[256 * 19];
    int n = blockIdx.y;
    int pixbase = blockIdx.x * 8;
    int t = threadIdx.x;
    if (t < 144) {
        int p = t / 18, j = t % 18;
        int ci = j / 9, tap = j % 9;
        int pix = pixbase + p;
        int y = pix / 56, x = pix % 56;
        int yy = y + tap / 3 - 1, xx = x + tap % 3 - 1;
        float v = 0.f;
        if ((unsigned)yy < 56u && (unsigned)xx < 56u)
            v = pm[((size_t)n * 2 + ci) * NPIX + yy * 56 + xx];
        sT[p][j] = v;
    }
    for (int idx = t; idx < 4608; idx += 256) {
        int co = idx / 18, j = idx % 18;
        sW1[co * 19 + j] = w[idx];
    }
    __syncthreads();
    int co = t;
    float bias = b[co];
#pragma unroll
    for (int p = 0; p < 8; p++) {
        float acc = bias;
#pragma unroll
        for (int j = 0; j < 18; j++) acc += sT[p][j] * sW1[co * 19 + j];
        acc = fmaxf(acc, 0.f);
        out[((size_t)n * NPIX + pixbase + p) * 256 + co] = f2b(acc);
    }
}

// ---------------- conv8p: counted-vmcnt pipelined 8-wave conv (TAPS=9) ------
// v7 (T3/T4 port): 128co x 448px block, 8 waves (mih=wv>>2 co-half,
// wpx=wv&3 px-quarter), acc[4][7]. LDS: sIn dbuf 2x37.1KB + sWa (taps0-3,
// 32KB) + sWb (taps4-8, 40KB) + 1KB trash = 149KB -> 1 block/CU, 8 waves =
// 2 waves/SIMD. NO __syncthreads (each would vmcnt(0)-drain the pipeline);
// raw s_barrier + counted vmcnt. Per-wave stage sizes UNIFORM by design:
// a=4, b=5, I=5 DMAs (skipped halo rows / past-end stages are redirected to
// the trash slot, never elided, so the vmcnt ledger holds on every block).
// Ledger (steady state, outstanding after each wait):
//   P0 wait vmcnt(10): drains a(ch)           keeps I(ch+1)[5]+b(ch)[5]
//   P1 wait vmcnt(4) : drains I(ch+1),b(ch)   keeps a(ch+1)[4]
// Every stage has >= one full compute phase (~2.2K cyc) to land (HBM ~900).
// PAIRED dispatch: blockIdx.z >= zsplit selects parameter set B.
__global__ __launch_bounds__(512, 2) void conv8p_mfma(
    const unsigned short* __restrict__ in,   // (NI,3136,256) bf16  (set A)
    const unsigned short* __restrict__ wp,   // [2][8][9][8][64][8] bf16
    const float* __restrict__ bias,
    unsigned short* __restrict__ out,        // bf16 NHWC
    const unsigned short* __restrict__ inB,  // parameter set B (paired half)
    const unsigned short* __restrict__ wpB,
    const float* __restrict__ biasB,
    unsigned short* __restrict__ outB,
    int zsplit)
{
    constexpr int SIN_SHORTS = 10 * 58 * 32;

    __shared__ unsigned short sIn[2 * SIN_SHORTS];   // 74240 B, ping-pong
    __shared__ unsigned short sWa[32 * 512];         // taps 0..3, 32768 B
    __shared__ unsigned short sWb[40 * 512];         // taps 4..8, 40960 B
    __shared__ unsigned short sTrash[512];           // 1024 B dummy-DMA sink

    const int r0 = blockIdx.x * 8;     // row base; bx==7 is an XCD-pad dummy
    if (r0 >= 56) return;
    const int tid = threadIdx.x;
    const int lane = tid & 63;
    const int wv = tid >> 6;           // 0..7
    const int mih = wv >> 2;           // co half (64co each)
    const int wpx = wv & 3;            // px quarter (112px each)
    const int col = lane & 15;
    const int quad = lane >> 4;
    const int cb = blockIdx.y;         // 128-cout block (0/1)

    int n = blockIdx.z;
    const unsigned short* inP = in;
    const unsigned short* wpP = wp;
    const float* biasP = bias;
    unsigned short* outP = out;
    if (n >= zsplit) {
        n -= zsplit;
        inP = inB; wpP = wpB; biasP = biasB; outP = outB;
    }

    const unsigned short* inN = inP + (size_t)n * NPIX * 256;
    const unsigned short* wcb = wpP + (size_t)cb * 8 * 72 * 512;

    // per-lane B-frag row offsets (y*58 + x)
    int rowoff[7];
#pragma unroll
    for (int nj = 0; nj < 7; nj++) {
        int pxl = wpx * 112 + nj * 16 + col;
        int yl = pxl / 56;
        rowoff[nj] = yl * 58 + (pxl - yl * 56);
    }
    const int qoff = quad * 8;
    const int laneSrc = (lane >> 2) * 256 + (lane & 3) * 8;

    // -- staging (uniform per-wave DMA counts; ch>7 => dummy to trash) --
    auto stage_a = [&](int ch) {                       // 4 DMAs/wave
        const bool dummy = (ch > 7);
        const unsigned short* wchunk = wcb + (size_t)(dummy ? 0 : ch) * 72 * 512;
#pragma unroll
        for (int i = 0; i < 4; i++) {
            int it = wv + 8 * i;                       // 0..31 (taps 0..3)
            async_copy16(wchunk + it * 512 + lane * 8,
                         dummy ? (unsigned short*)sTrash : (sWa + it * 512));
        }
    };
    auto stage_b = [&](int ch) {                       // 5 DMAs/wave
        const unsigned short* wchunk = wcb + (size_t)ch * 72 * 512;
#pragma unroll
        for (int i = 0; i < 5; i++) {
            int it = 32 + wv + 8 * i;                  // 32..71 (taps 4..8)
            async_copy16(wchunk + it * 512 + lane * 8, sWb + (it - 32) * 512);
        }
    };
    auto stage_I = [&](int ch) {                       // 5 DMAs/wave
        const bool dummy = (ch > 7);
        unsigned short* dst0 = sIn + (ch & 1) * SIN_SHORTS;
        const int c0 = (dummy ? 0 : ch) * 32;
#pragma unroll
        for (int i = 0; i < 5; i++) {
            int s = wv + 8 * i;                        // 0..39
            int ry = s >> 2, k = s & 3;
            int gy = r0 + ry - 1;
            bool valid = ((unsigned)gy < 56u) && !dummy;
            const unsigned short* src =
                inN + (size_t)(valid ? gy : 0) * 14336 + k * 4096 + c0 + laneSrc;
            unsigned short* dst = valid ? (dst0 + ry * 1856 + 32 + k * 512)
                                        : (unsigned short*)sTrash;
            if (k < 3 || lane < 32)                    // k wave-uniform; always issues
                async_copy16(src, dst);
        }
    };

    // prezero both halves: pads + out-of-image halo rows stay 0 all chunks
    for (int i = tid * 8; i < 2 * SIN_SHORTS; i += 512 * 8)
        *(int4*)(sIn + i) = (int4){0, 0, 0, 0};
    asm volatile("s_waitcnt lgkmcnt(0)" ::: "memory");
    BARRIER();   // zeros visible before any DMA lands / any compute reads pads

    float4v acc[4][7];
#pragma unroll
    for (int mi = 0; mi < 4; mi++)
#pragma unroll
        for (int nj = 0; nj < 7; nj++) acc[mi][nj] = (float4v){0.f, 0.f, 0.f, 0.f};

    // prologue issues (order matters for the vmcnt ledger): I0,a0 | I1,b0
    stage_I(0); stage_a(0); stage_I(1); stage_b(0);    // 5+4+5+5 = 19 in flight

    for (int ch = 0; ch < 8; ch++) {
        const int iOff = (ch & 1) * SIN_SHORTS;

        WAIT_VMCNT(10);            // a(ch)+I(ch) landed; I(ch+1),b(ch) in flight
        BARRIER();                 // ...landed for ALL waves
        __builtin_amdgcn_s_setprio(1);
#pragma unroll
        for (int tap = 0; tap < 4; tap++) {            // P0: taps 0..3 (sWa)
            const int coff = ((tap / 3) * 58 + (tap % 3)) * 32;
            short8v a[4], b[7];
#pragma unroll
            for (int mi = 0; mi < 4; mi++)
                a[mi] = *(const short8v*)(sWa + ((tap * 8 + mih * 4 + mi) * 64 + lane) * 8);
#pragma unroll
            for (int nj = 0; nj < 7; nj++)
                b[nj] = *(const short8v*)(sIn + iOff + rowoff[nj] * 32 + coff + qoff);
#pragma unroll
            for (int mi = 0; mi < 4; mi++)
#pragma unroll
                for (int nj = 0; nj < 7; nj++)
                    acc[mi][nj] = __builtin_amdgcn_mfma_f32_16x16x32_bf16(
                        a[mi], b[nj], acc[mi][nj], 0, 0, 0);
        }
        __builtin_amdgcn_s_setprio(0);
        BARRIER();                 // all waves done reading sWa
        stage_a(ch + 1);           // refill sWa; flies under P1 (ch==7: dummy)

        WAIT_VMCNT(4);             // b(ch)+I(ch+1) landed; a(ch+1) in flight
        BARRIER();                 // ...landed for ALL waves
        __builtin_amdgcn_s_setprio(1);
#pragma unroll
        for (int tap = 4; tap < 9; tap++) {            // P1: taps 4..8 (sWb)
            const int coff = ((tap / 3) * 58 + (tap % 3)) * 32;
            short8v a[4], b[7];
#pragma unroll
            for (int mi = 0; mi < 4; mi++)
                a[mi] = *(const short8v*)(sWb + (((tap - 4) * 8 + mih * 4 + mi) * 64 + lane) * 8);
#pragma unroll
            for (int nj = 0; nj < 7; nj++)
                b[nj] = *(const short8v*)(sIn + iOff + rowoff[nj] * 32 + coff + qoff);
#pragma unroll
            for (int mi = 0; mi < 4; mi++)
#pragma unroll
                for (int nj = 0; nj < 7; nj++)
                    acc[mi][nj] = __builtin_amdgcn_mfma_f32_16x16x32_bf16(
                        a[mi], b[nj], acc[mi][nj], 0, 0, 0);
        }
        __builtin_amdgcn_s_setprio(0);
        if (ch < 7) {
            BARRIER();             // all waves done reading sWb + sIn[half]
            stage_I(ch + 2);       // refill this sIn half (ch==6: dummy I(8))
            stage_b(ch + 1);       // refill sWb; flies under next P0
        }
    }

    // epilogue: D row = quad*4+reg (cout), col = pixel; relu+bias
    unsigned short* outT = outP + ((size_t)n * NPIX + r0 * 56 + wpx * 112) * 256
                         + cb * 128 + mih * 64;
#pragma unroll
    for (int mi = 0; mi < 4; mi++) {
        float4v bv = *(const float4v*)(biasP + cb * 128 + mih * 64 + mi * 16 + quad * 4);
#pragma unroll
        for (int nj = 0; nj < 7; nj++) {
            float v0 = fmaxf(acc[mi][nj][0] + bv[0], 0.f);
            float v1 = fmaxf(acc[mi][nj][1] + bv[1], 0.f);
            float v2 = fmaxf(acc[mi][nj][2] + bv[2], 0.f);
            float v3 = fmaxf(acc[mi][nj][3] + bv[3], 0.f);
            uint2 pk;
            pk.x = (unsigned)f2b(v0) | ((unsigned)f2b(v1) << 16);
            pk.y = (unsigned)f2b(v2) | ((unsigned)f2b(v3) << 16);
            *(uint2*)(outT + ((size_t)(nj * 16 + col)) * 256 + mi * 16 + quad * 4) = pk;
        }
    }
}

// ---------------- conv8: v6 8-wave kernel (used for the 1x1 DW only) --------
template <int TAPS, bool RELU, bool HASB>
__global__ __launch_bounds__(512, 2) void conv8_mfma(
    const unsigned short* __restrict__ in,
    const unsigned short* __restrict__ wp,   // [2][8][TAPS][8][64][8] bf16
    const float* __restrict__ bias,
    unsigned short* __restrict__ out,
    const unsigned short* __restrict__ inB,
    const unsigned short* __restrict__ wpB,
    const float* __restrict__ biasB,
    unsigned short* __restrict__ outB,
    int zsplit)
{
    constexpr int W_ITERS = TAPS * 8;
    constexpr int SIN_SHORTS = (TAPS == 9) ? 10 * 58 * 32 : 448 * 32;

    __shared__ unsigned short sIn[2 * SIN_SHORTS];
    __shared__ unsigned short sW[W_ITERS * 512];

    const int r0 = blockIdx.x * 8;
    if (r0 >= 56) return;
    const int tid = threadIdx.x;
    const int lane = tid & 63;
    const int wv = tid >> 6;
    const int mih = wv >> 2;
    const int wpx = wv & 3;
    const int col = lane & 15;
    const int quad = lane >> 4;
    const int cb = blockIdx.y;

    int n = blockIdx.z;
    const unsigned short* inP = in;
    const unsigned short* wpP = wp;
    const float* biasP = bias;
    unsigned short* outP = out;
    if (n >= zsplit) {
        n -= zsplit;
        inP = inB; wpP = wpB; biasP = biasB; outP = outB;
    }

    const unsigned short* inN = inP + (size_t)n * NPIX * 256;
    const unsigned short* wcb = wpP + (size_t)cb * 8 * W_ITERS * 512;

    int rowoff[7];
#pragma unroll
    for (int nj = 0; nj < 7; nj++) {
        int pxl = wpx * 112 + nj * 16 + col;
        if (TAPS == 9) {
            int yl = pxl / 56;
            rowoff[nj] = yl * 58 + (pxl - yl * 56);
        } else {
            rowoff[nj] = pxl;
        }
    }
    const int qoff = quad * 8;
    const int laneSrc = (lane >> 2) * 256 + (lane & 3) * 8;

    auto stageW = [&](int ch) {
        const unsigned short* wchunk = wcb + (size_t)ch * W_ITERS * 512;
#pragma unroll
        for (int it = wv; it < W_ITERS; it += 8)
            async_copy16(wchunk + it * 512 + lane * 8, sW + it * 512);
    };
    auto stageI = [&](int ch, int half) {
        const int c0 = ch * 32;
        unsigned short* dst = sIn + half * SIN_SHORTS;
        if (TAPS == 9) {
#pragma unroll
            for (int s = wv; s < 40; s += 8) {
                int ry = s >> 2, k = s & 3;
                int gy = r0 + ry - 1;
                if ((unsigned)gy < 56u && (k < 3 || lane < 32))
                    async_copy16(inN + (size_t)gy * 14336 + k * 4096 + c0 + laneSrc,
                                 dst + ry * 1856 + 32 + k * 512);
            }
        } else {
#pragma unroll
            for (int s = wv; s < 28; s += 8)
                async_copy16(inN + (size_t)r0 * 14336 + s * 4096 + c0 + laneSrc,
                             dst + s * 512);
        }
    };

    if (TAPS == 9) {
        for (int i = tid * 8; i < 2 * SIN_SHORTS; i += 512 * 8)
            *(int4*)(sIn + i) = (int4){0, 0, 0, 0};
        __syncthreads();
    }

    float4v acc[4][7];
#pragma unroll
    for (int mi = 0; mi < 4; mi++)
#pragma unroll
        for (int nj = 0; nj < 7; nj++) acc[mi][nj] = (float4v){0.f, 0.f, 0.f, 0.f};

    stageW(0);
    stageI(0, 0);

    for (int ch = 0; ch < 8; ch++) {
        __syncthreads();
        if (ch < 7) stageI(ch + 1, (ch + 1) & 1);
        const int iOff = (ch & 1) * SIN_SHORTS;
#pragma unroll
        for (int tap = 0; tap < TAPS; tap++) {
            const int coff = (TAPS == 9) ? ((tap / 3) * 58 + (tap % 3)) * 32 : 0;
            short8v a[4], b[7];
#pragma unroll
            for (int mi = 0; mi < 4; mi++)
                a[mi] = *(const short8v*)(sW + ((tap * 8 + mih * 4 + mi) * 64 + lane) * 8);
#pragma unroll
            for (int nj = 0; nj < 7; nj++)
                b[nj] = *(const short8v*)(sIn + iOff + rowoff[nj] * 32 + coff + qoff);
#pragma unroll
            for (int mi = 0; mi < 4; mi++)
#pragma unroll
                for (int nj = 0; nj < 7; nj++)
                    acc[mi][nj] = __builtin_amdgcn_mfma_f32_16x16x32_bf16(
                        a[mi], b[nj], acc[mi][nj], 0, 0, 0);
        }
        if (ch < 7) {
            __syncthreads();
            stageW(ch + 1);
        }
    }

    unsigned short* outT = outP + ((size_t)n * NPIX + r0 * 56 + wpx * 112) * 256
                         + cb * 128 + mih * 64;
#pragma unroll
    for (int mi = 0; mi < 4; mi++) {
        float4v bv = (float4v){0.f, 0.f, 0.f, 0.f};
        if (HASB) bv = *(const float4v*)(biasP + cb * 128 + mih * 64 + mi * 16 + quad * 4);
#pragma unroll
        for (int nj = 0; nj < 7; nj++) {
            float v0 = acc[mi][nj][0] + bv[0];
            float v1 = acc[mi][nj][1] + bv[1];
            float v2 = acc[mi][nj][2] + bv[2];
            float v3 = acc[mi][nj][3] + bv[3];
            if (RELU) {
                v0 = fmaxf(v0, 0.f); v1 = fmaxf(v1, 0.f);
                v2 = fmaxf(v2, 0.f); v3 = fmaxf(v3, 0.f);
            }
            uint2 pk;
            pk.x = (unsigned)f2b(v0) | ((unsigned)f2b(v1) << 16);
            pk.y = (unsigned)f2b(v2) | ((unsigned)f2b(v3) << 16);
            *(uint2*)(outT + ((size_t)(nj * 16 + col)) * 256 + mi * 16 + quad * 4) = pk;
        }
    }
}

// ---------------- v4 conv (FUSE only): 4-wave, 2 blocks/CU ------------------
// Kept verbatim for M3: heavy p2d/pooled epilogue overlaps across 2 resident
// blocks; uses the OLD 64-co weight layout (pack wi==5).
template <int TAPS, bool RELU, bool HASB, bool FUSE>
__global__ __launch_bounds__(256, 2) void conv_mfma(
    const unsigned short* __restrict__ in,
    const unsigned short* __restrict__ wp,   // [4][8][TAPS][4][64][8] bf16
    const float* __restrict__ bias,
    unsigned short* __restrict__ out,
    const unsigned short* __restrict__ inB,
    const unsigned short* __restrict__ wpB,
    const float* __restrict__ biasB,
    unsigned short* __restrict__ outB,
    int zsplit,
    const unsigned short* __restrict__ emb,  // (FUSE) bf16 NHWC
    float* __restrict__ dout)                // (FUSE) pooled[6144] + p2d fp32 NCHW
{
    constexpr int W_ITERS = TAPS * 4;
    constexpr int SIN_SHORTS = (TAPS == 9) ? 10 * 58 * 32 : 448 * 32;

    __shared__ unsigned short sIn[SIN_SHORTS];
    __shared__ unsigned short sW[W_ITERS * 512];

    const int r0 = blockIdx.x * 8;
    if (r0 >= 56) return;
    const int tid = threadIdx.x;
    const int lane = tid & 63;
    const int wv = tid >> 6;
    const int col = lane & 15;
    const int quad = lane >> 4;
    const int cb = blockIdx.y;

    int n = blockIdx.z;
    const unsigned short* inP = in;
    const unsigned short* wpP = wp;
    const float* biasP = bias;
    unsigned short* outP = out;
    if (n >= zsplit) {
        n -= zsplit;
        inP = inB; wpP = wpB; biasP = biasB; outP = outB;
    }

    const unsigned short* inN = inP + (size_t)n * NPIX * 256;
    const unsigned short* wcb = wpP + (size_t)cb * 8 * W_ITERS * 512;

    int rowoff[7];
#pragma unroll
    for (int nj = 0; nj < 7; nj++) {
        int pxl = wv * 112 + nj * 16 + col;
        if (TAPS == 9) {
            int yl = pxl / 56;
            rowoff[nj] = yl * 58 + (pxl - yl * 56);
        } else {
            rowoff[nj] = pxl;
        }
    }
    const int qoff = quad * 8;
    const int laneSrc = (lane >> 2) * 256 + (lane & 3) * 8;

    if (TAPS == 9) {
        for (int i = tid * 8; i < SIN_SHORTS; i += 2048)
            *(int4*)(sIn + i) = (int4){0, 0, 0, 0};
    }

    float4v acc[4][7];
#pragma unroll
    for (int mi = 0; mi < 4; mi++)
#pragma unroll
        for (int nj = 0; nj < 7; nj++) acc[mi][nj] = (float4v){0.f, 0.f, 0.f, 0.f};

    for (int ch = 0; ch < 8; ch++) {
        const int c0 = ch * 32;
        __syncthreads();
        const unsigned short* wchunk = wcb + (size_t)ch * W_ITERS * 512;
#pragma unroll
        for (int it = wv; it < W_ITERS; it += 4)
            async_copy16(wchunk + it * 512 + lane * 8, sW + it * 512);
        if (TAPS == 9) {
#pragma unroll
            for (int ry = 0; ry < 10; ry++) {
                int k = (wv - ry) & 3;
                int gy = r0 + ry - 1;
                if ((unsigned)gy < 56u && (k < 3 || lane < 32))
                    async_copy16(inN + (size_t)gy * 14336 + k * 4096 + c0 + laneSrc,
                                 sIn + ry * 1856 + 32 + k * 512);
            }
        } else {
#pragma unroll
            for (int k = 0; k < 7; k++) {
                int it = wv + k * 4;
                async_copy16(inN + (size_t)r0 * 14336 + it * 4096 + c0 + laneSrc,
                             sIn + it * 512);
            }
        }
        __syncthreads();
#pragma unroll
        for (int tap = 0; tap < TAPS; tap++) {
            const int coff = (TAPS == 9) ? ((tap / 3) * 58 + (tap % 3)) * 32 : 0;
            short8v a[4], b[7];
#pragma unroll
            for (int mi = 0; mi < 4; mi++)
                a[mi] = *(const short8v*)(sW + ((tap * 4 + mi) * 64 + lane) * 8);
#pragma unroll
            for (int nj = 0; nj < 7; nj++)
                b[nj] = *(const short8v*)(sIn + rowoff[nj] * 32 + coff + qoff);
#pragma unroll
            for (int mi = 0; mi < 4; mi++)
#pragma unroll
                for (int nj = 0; nj < 7; nj++)
                    acc[mi][nj] = __builtin_amdgcn_mfma_f32_16x16x32_bf16(
                        a[mi], b[nj], acc[mi][nj], 0, 0, 0);
        }
    }

    if (!FUSE) {
        unsigned short* outT = outP + ((size_t)n * NPIX + r0 * 56 + wv * 112) * 256 + cb * 64;
#pragma unroll
        for (int mi = 0; mi < 4; mi++) {
            float4v bv = (float4v){0.f, 0.f, 0.f, 0.f};
            if (HASB) bv = *(const float4v*)(biasP + cb * 64 + mi * 16 + quad * 4);
#pragma unroll
            for (int nj = 0; nj < 7; nj++) {
                float v0 = acc[mi][nj][0] + bv[0];
                float v1 = acc[mi][nj][1] + bv[1];
                float v2 = acc[mi][nj][2] + bv[2];
                float v3 = acc[mi][nj][3] + bv[3];
                if (RELU) {
                    v0 = fmaxf(v0, 0.f); v1 = fmaxf(v1, 0.f);
                    v2 = fmaxf(v2, 0.f); v3 = fmaxf(v3, 0.f);
                }
                uint2 pk;
                pk.x = (unsigned)f2b(v0) | ((unsigned)f2b(v1) << 16);
                pk.y = (unsigned)f2b(v2) | ((unsigned)f2b(v3) << 16);
                *(uint2*)(outT + ((size_t)(nj * 16 + col)) * 256 + mi * 16 + quad * 4) = pk;
            }
        }
    } else {
        const int pixBase = r0 * 56 + wv * 112;
        float* p2d = dout + 6144 + (size_t)n * CDIM * NPIX;
        float sums[4][4];
#pragma unroll
        for (int mi = 0; mi < 4; mi++)
#pragma unroll
            for (int q = 0; q < 4; q++) sums[mi][q] = 0.f;
#pragma unroll
        for (int mi = 0; mi < 4; mi++) {
            float4v bv = *(const float4v*)(biasP + cb * 64 + mi * 16 + quad * 4);
            const int co0 = cb * 64 + mi * 16 + quad * 4;
#pragma unroll
            for (int nj = 0; nj < 7; nj++) {
                int pix = pixBase + nj * 16 + col;
                uint2 e = *(const uint2*)(emb + ((size_t)n * NPIX + pix) * 256 + co0);
                float v0 = fmaxf(acc[mi][nj][0] + bv[0], 0.f) + b2f((unsigned short)(e.x & 0xFFFF));
                float v1 = fmaxf(acc[mi][nj][1] + bv[1], 0.f) + b2f((unsigned short)(e.x >> 16));
                float v2 = fmaxf(acc[mi][nj][2] + bv[2], 0.f) + b2f((unsigned short)(e.y & 0xFFFF));
                float v3 = fmaxf(acc[mi][nj][3] + bv[3], 0.f) + b2f((unsigned short)(e.y >> 16));
                p2d[(size_t)(co0 + 0) * NPIX + pix] = v0;
                p2d[(size_t)(co0 + 1) * NPIX + pix] = v1;
                p2d[(size_t)(co0 + 2) * NPIX + pix] = v2;
                p2d[(size_t)(co0 + 3) * NPIX + pix] = v3;
                sums[mi][0] += v0; sums[mi][1] += v1;
                sums[mi][2] += v2; sums[mi][3] += v3;
            }
        }
#pragma unroll
        for (int mi = 0; mi < 4; mi++)
#pragma unroll
            for (int q = 0; q < 4; q++) {
                float s = sums[mi][q];
                s += __shfl_down(s, 8, 16);
                s += __shfl_down(s, 4, 16);
                s += __shfl_down(s, 2, 16);
                s += __shfl_down(s, 1, 16);
                if (col == 0)
                    atomicAdd(dout + n * CDIM + cb * 64 + mi * 16 + quad * 4 + q,
                              s * (1.f / 3136.f));
            }
    }
}

// ---------------- i_features NCHW fp32 -> NHWC bf16 -------------------------
__global__ __launch_bounds__(256) void transpose_fI(
    const float* __restrict__ feat, unsigned short* __restrict__ dst)
{
    __shared__ float s[64][65];
    int fi = blockIdx.z;
    int p0 = blockIdx.x * 64;
    int c0 = blockIdx.y * 64;
    int t = threadIdx.x;
    int pl = t & 63, cq = t >> 6;
#pragma unroll
    for (int i = 0; i < 16; i++) {
        int c = cq + i * 4;
        s[pl][c] = feat[((size_t)fi * 256 + c0 + c) * NPIX + p0 + pl];
    }
    __syncthreads();
    int cl = t & 63, pq = t >> 6;
#pragma unroll
    for (int i = 0; i < 16; i++) {
        int p = pq + i * 4;
        dst[((size_t)fi * NPIX + p0 + p) * 256 + c0 + cl] = f2b(s[p][cl]);
    }
}

// ---------------- deform sampling of Z (NHWC bf16) + db ---------------------
__global__ __launch_bounds__(256) void deform_kernel(
    const unsigned short* __restrict__ Z,   // (8,3136,256) bf16
    const float* __restrict__ pm,           // (24,2,3136) fp32
    const float* __restrict__ db,
    unsigned short* __restrict__ out)       // (24,3136,256) bf16
{
    int n = blockIdx.y;
    int t = threadIdx.x;
    int pix = blockIdx.x * 8 + (t >> 5);
    int g = t & 31;                  // 8-channel group
    int fi = n / 3;
    int y = pix / 56, x = pix % 56;
    float dy = pm[((size_t)n * 2 + 0) * NPIX + pix];
    float dx = pm[((size_t)n * 2 + 1) * NPIX + pix];
    float gy = (float)y + dy, gx = (float)x + dx;
    float y0f = floorf(gy), x0f = floorf(gx);
    float ty = gy - y0f, tx = gx - x0f;
    int y0 = (int)y0f, x0 = (int)x0f, y1 = y0 + 1, x1 = x0 + 1;
    bool vy0 = (unsigned)y0 < 56u, vy1 = (unsigned)y1 < 56u;
    bool vx0 = (unsigned)x0 < 56u, vx1 = (unsigned)x1 < 56u;
    float w00 = (1.f - ty) * (1.f - tx) * (vy0 && vx0 ? 1.f : 0.f);
    float w01 = (1.f - ty) * tx * (vy0 && vx1 ? 1.f : 0.f);
    float w10 = ty * (1.f - tx) * (vy1 && vx0 ? 1.f : 0.f);
    float w11 = ty * tx * (vy1 && vx1 ? 1.f : 0.f);
    int y0c = vy0 ? y0 : 0, y1c = vy1 ? y1 : 0;
    int x0c = vx0 ? x0 : 0, x1c = vx1 ? x1 : 0;
    const unsigned short* Zf = Z + (size_t)fi * NPIX * 256 + g * 8;
    const unsigned short* p00 = Zf + (size_t)(y0c * 56 + x0c) * 256;
    const unsigned short* p01 = Zf + (size_t)(y0c * 56 + x1c) * 256;
    const unsigned short* p10 = Zf + (size_t)(y1c * 56 + x0c) * 256;
    const unsigned short* p11 = Zf + (size_t)(y1c * 56 + x1c) * 256;
    unsigned short r[8];
#pragma unroll
    for (int j = 0; j < 8; j++) {
        float v = b2f(p00[j]) * w00 + b2f(p01[j]) * w01 +
                  b2f(p10[j]) * w10 + b2f(p11[j]) * w11;
        v += db[g * 8 + j];
        r[j] = f2b(v);
    }
    *(int4*)(out + ((size_t)n * NPIX + pix) * 256 + g * 8) = *(int4*)r;
}

extern "C" void kernel_launch(void* const* d_in, const int* in_sizes, int n_in,
                              void* d_out, int out_size, void* d_ws, size_t ws_size,
                              hipStream_t stream)
{
    const float* i_features = (const float*)d_in[1];
    const float* p_motions  = (const float*)d_in[2];
    const float* dw  = (const float*)d_in[3];
    const float* db  = (const float*)d_in[4];
    const float* mw1 = (const float*)d_in[5];
    const float* mb1 = (const float*)d_in[6];
    const float* mw2 = (const float*)d_in[7];
    const float* mb2 = (const float*)d_in[8];
    const float* mw3 = (const float*)d_in[9];
    const float* mb3 = (const float*)d_in[10];
    const float* ew1 = (const float*)d_in[11];
    const float* eb1 = (const float*)d_in[12];
    const float* ew2 = (const float*)d_in[13];
    const float* eb2 = (const float*)d_in[14];
    const float* ew3 = (const float*)d_in[15];
    const float* eb3 = (const float*)d_in[16];
    const float* ew4 = (const float*)d_in[17];
    const float* eb4 = (const float*)d_in[18];
    float* out = (float*)d_out;

    // workspace layout (bytes)
    const size_t SZ_PM  = 602112;
    const size_t SZ_WPK = 7208960;
    const size_t SZ_ACT = 38535168;   // 24-frame bf16 NHWC
    char* p = (char*)d_ws;
    float* pm = (float*)p;            p += SZ_PM;
    unsigned short* wpk = (unsigned short*)p;   // 6x 3x3 (contiguous) + 1x1
    unsigned short* wpE2 = wpk + 0 * 589824;
    unsigned short* wpE3 = wpk + 1 * 589824;
    unsigned short* wpE4 = wpk + 2 * 589824;
    unsigned short* wpM1 = wpk + 3 * 589824;
    unsigned short* wpM2 = wpk + 4 * 589824;
    unsigned short* wpM3 = wpk + 5 * 589824;
    unsigned short* wpDW = wpk + 6 * 589824;
    p += SZ_WPK;
    unsigned short* bufA = (unsigned short*)p; p += SZ_ACT;
    unsigned short* bufB = (unsigned short*)p; p += SZ_ACT;
    unsigned short* bufC = (unsigned short*)p; p += SZ_ACT;
    unsigned short* bufD = (unsigned short*)p;     // only used if ws permits

    const bool paired = ws_size >= SZ_PM + SZ_WPK + 4 * SZ_ACT;

    hipMemsetAsync(out, 0, 6144 * sizeof(float), stream);  // pooled accumulators

    resize_pm_kernel<<<(NN * 2 * NPIX + 255) / 256, 256, 0, stream>>>(p_motions, pm);
    pack_all_kernel<<<6 * 2304 + 256, 256, 0, stream>>>(
        ew2, ew3, ew4, mw1, mw2, mw3, dw, wpk);

    dim3 cg24(8, 2, NN), cg48(8, 2, 2 * NN), cg8(8, 2, 8);
    dim3 cgF(8, 4, NN);   // FUSE conv (old 4-wave kernel)

    if (paired) {
        // ew1 -> A ; E2: A -> B (pipelined)
        ew1_kernel<<<dim3(392, NN), 256, 0, stream>>>(pm, ew1, eb1, bufA);
        conv8p_mfma<<<cg24, 512, 0, stream>>>(
            bufA, wpE2, eb2, bufB,  bufA, wpE2, eb2, bufB, NN);
        // A dead -> overlay fI at A[0], Z at A[+12.85MB]
        unsigned short* fI = bufA;
        unsigned short* Zb = bufA + (size_t)8 * NPIX * 256;
        transpose_fI<<<dim3(49, 4, 8), 256, 0, stream>>>(i_features, fI);
        conv8_mfma<1, false, false><<<cg8, 512, 0, stream>>>(
            fI, wpDW, nullptr, Zb,  fI, wpDW, nullptr, Zb, NN);
        deform_kernel<<<dim3(392, NN), 256, 0, stream>>>(Zb, pm, db, bufC);
        // D2 pair: E3: B -> A  ||  M1: C -> D
        conv8p_mfma<<<cg48, 512, 0, stream>>>(
            bufB, wpE3, eb3, bufA,  bufC, wpM1, mb1, bufD, NN);
        // D3 pair: E4: A -> B (emb)  ||  M2: D -> C
        conv8p_mfma<<<cg48, 512, 0, stream>>>(
            bufA, wpE4, eb4, bufB,  bufD, wpM2, mb2, bufC, NN);
        // final: M3 fused (old kernel, old weight layout), reads C + emb(B)
        conv_mfma<9, true, true, true><<<cgF, 256, 0, stream>>>(
            bufC, wpM3, mb3, nullptr,  bufC, wpM3, mb3, nullptr, NN, bufB, out);
    } else {
        // fallback: serial sequence with 3 buffers (A, B, C=emb)
        ew1_kernel<<<dim3(392, NN), 256, 0, stream>>>(pm, ew1, eb1, bufA);
        conv8p_mfma<<<cg24, 512, 0, stream>>>(
            bufA, wpE2, eb2, bufB,  bufA, wpE2, eb2, bufB, NN);
        conv8p_mfma<<<cg24, 512, 0, stream>>>(
            bufB, wpE3, eb3, bufA,  bufB, wpE3, eb3, bufA, NN);
        conv8p_mfma<<<cg24, 512, 0, stream>>>(
            bufA, wpE4, eb4, bufC,  bufA, wpE4, eb4, bufC, NN);
        transpose_fI<<<dim3(49, 4, 8), 256, 0, stream>>>(i_features, bufA);
        conv8_mfma<1, false, false><<<cg8, 512, 0, stream>>>(
            bufA, wpDW, nullptr, bufB,  bufA, wpDW, nullptr, bufB, NN);
        deform_kernel<<<dim3(392, NN), 256, 0, stream>>>(bufB, pm, db, bufA);
        conv8p_mfma<<<cg24, 512, 0, stream>>>(
            bufA, wpM1, mb1, bufB,  bufA, wpM1, mb1, bufB, NN);
        conv8p_mfma<<<cg24, 512, 0, stream>>>(
            bufB, wpM2, mb2, bufA,  bufB, wpM2, mb2, bufA, NN);
        conv_mfma<9, true, true, true><<<cgF, 256, 0, stream>>>(
            bufA, wpM3, mb3, nullptr,  bufA, wpM3, mb3, nullptr, NN, bufC, out);
    }
}

// Round 8
// 676.843 us; speedup vs baseline: 1.1218x; 1.1218x over previous
//
#include <hip/hip_runtime.h>

// Shapes: imgs(2,16,3,224,224)[shape only], i_features(8,256,56,56) fp32,
// p_motions(2,12,2,112,112) fp32 -> N=24 frames, C=256, H=W=56, k=3.
#define NPIX 3136
#define NN   24
#define CDIM 256

typedef __attribute__((ext_vector_type(8))) short short8v;   // 8 bf16 (A/B frag)
typedef __attribute__((ext_vector_type(4))) float float4v;   // 4 fp32 (C/D frag)

typedef __attribute__((address_space(1))) const void gvoid;
typedef __attribute__((address_space(3))) void lvoid;
static __device__ __forceinline__ void async_copy16(const void* g, void* l) {
    // lane's 16B lands at l + lane*16 (wave-uniform LDS base)
    __builtin_amdgcn_global_load_lds((gvoid*)g, (lvoid*)l, 16, 0, 0);
}

static __device__ __forceinline__ unsigned short f2b(float f) {
    unsigned int u = __float_as_uint(f);
    u = (u + 0x7FFFu + ((u >> 16) & 1u)) >> 16;   // RNE
    return (unsigned short)u;
}
static __device__ __forceinline__ float b2f(unsigned short h) {
    return __uint_as_float(((unsigned int)h) << 16);
}

// ---------------- resize(112->56)*scale == avg2x2 * 0.0625 ------------------
__global__ __launch_bounds__(256) void resize_pm_kernel(
    const float* __restrict__ pmo, float* __restrict__ pm)
{
    int idx = blockIdx.x * 256 + threadIdx.x;
    if (idx >= NN * 2 * NPIX) return;
    int x = idx % 56, y = (idx / 56) % 56, nc = idx / NPIX;
    const float* src = pmo + (size_t)nc * 112 * 112 + (size_t)(2 * y) * 112 + 2 * x;
    pm[idx] = (src[0] + src[1] + src[112] + src[113]) * 0.0625f;
}

// ---------------- merged weight packing (6x 3x3 + 1x 1x1), v4 layout --------
// 3x3: dst [cb4][ch8][tap9][g4][lane64][8]; co=cb*64+g*16+(lane&15),
//      ci=ch*32+(lane>>4)*8+j. 1x1 same without tap. dsts contiguous in ws.
__global__ __launch_bounds__(256) void pack_all_kernel(
    const float* __restrict__ s0, const float* __restrict__ s1,
    const float* __restrict__ s2, const float* __restrict__ s3,
    const float* __restrict__ s4, const float* __restrict__ s5,
    const float* __restrict__ sdw, unsigned short* __restrict__ dstbase)
{
    int bx = blockIdx.x;
    if (bx < 6 * 2304) {
        int wi = bx / 2304;
        int d = (bx % 2304) * 256 + threadIdx.x;
        const float* w = (wi == 0) ? s0 : (wi == 1) ? s1 : (wi == 2) ? s2
                       : (wi == 3) ? s3 : (wi == 4) ? s4 : s5;
        int j = d & 7;
        int lane = (d >> 3) & 63;
        int g = (d >> 9) & 3;
        int e = d >> 11;
        int tap = e % 9;
        int f = e / 9;
        int ch = f & 7, cb = f >> 3;
        int co = cb * 64 + g * 16 + (lane & 15);
        int ci = ch * 32 + (lane >> 4) * 8 + j;
        dstbase[(size_t)wi * 589824 + d] = f2b(w[((size_t)co * 256 + ci) * 9 + tap]);
    } else {
        int d = (bx - 6 * 2304) * 256 + threadIdx.x;
        int j = d & 7;
        int lane = (d >> 3) & 63;
        int g = (d >> 9) & 3;
        int ch = (d >> 11) & 7;
        int cb = d >> 14;
        int co = cb * 64 + g * 16 + (lane & 15);
        int ci = ch * 32 + (lane >> 4) * 8 + j;
        dstbase[(size_t)6 * 589824 + d] = f2b(sdw[(size_t)co * 256 + ci]);
    }
}

// ---------------- merged ew1 conv + i_features transpose --------------------
// bx < ewBlocks: ew1 (Cin=2, K=18) fp32 direct -> bf16 NHWC + relu.
// bx >= ewBlocks (when doFI): NCHW fp32 -> NHWC bf16 transpose of i_features.
// Both are independent producers; merging absorbs the small transpose into
// the machine-filling ew1 dispatch (saves a serial launch).
__global__ __launch_bounds__(256) void ew1_fI_kernel(
    const float* __restrict__ pm, const float* __restrict__ w,   // (256,2,3,3)
    const float* __restrict__ b, unsigned short* __restrict__ outEw,
    const float* __restrict__ feat, unsigned short* __restrict__ outFI,
    int ewBlocks)
{
    __shared__ float sT[8][18];
    __shared__ float sW1[256 * 19];
    __shared__ float sTr[64][65];
    int bx = blockIdx.x;
    int t = threadIdx.x;
    if (bx < ewBlocks) {
        int n = bx / 392;
        int pixbase = (bx % 392) * 8;
        if (t < 144) {
            int p = t / 18, j = t % 18;
            int ci = j / 9, tap = j % 9;
            int pix = pixbase + p;
            int y = pix / 56, x = pix % 56;
            int yy = y + tap / 3 - 1, xx = x + tap % 3 - 1;
            float v = 0.f;
            if ((unsigned)yy < 56u && (unsigned)xx < 56u)
                v = pm[((size_t)n * 2 + ci) * NPIX + yy * 56 + xx];
            sT[p][j] = v;
        }
        for (int idx = t; idx < 4608; idx += 256) {
            int co = idx / 18, j = idx % 18;
            sW1[co * 19 + j] = w[idx];
        }
        __syncthreads();
        int co = t;
        float bias = b[co];
#pragma unroll
        for (int p = 0; p < 8; p++) {
            float acc = bias;
#pragma unroll
            for (int j = 0; j < 18; j++) acc += sT[p][j] * sW1[co * 19 + j];
            acc = fmaxf(acc, 0.f);
            outEw[((size_t)n * NPIX + pixbase + p) * 256 + co] = f2b(acc);
        }
    } else {
        int b2 = bx - ewBlocks;          // [0, 49*4*8)
        int fi = b2 / 196;
        int rem = b2 % 196;
        int c0 = (rem / 49) * 64;
        int p0 = (rem % 49) * 64;
        int pl = t & 63, cq = t >> 6;
#pragma unroll
        for (int i = 0; i < 16; i++) {
            int c = cq + i * 4;
            sTr[pl][c] = feat[((size_t)fi * 256 + c0 + c) * NPIX + p0 + pl];
        }
        __syncthreads();
        int cl = t & 63, pq = t >> 6;
#pragma unroll
        for (int i = 0; i < 16; i++) {
            int p = pq + i * 4;
            outFI[((size_t)fi * NPIX + p0 + p) * 256 + c0 + cl] = f2b(sTr[p][cl]);
        }
    }
}

// ---------------- v4 conv body (verbatim), as a template device fn ----------
// 64co x 448px tile, 4 waves each 64co x 112px, acc[4][7] (112 AGPR ->
// 2 waves/SIMD; LDS 74KB -> 2 blocks/CU = 8 waves/CU). This is the measured
// optimum: v5/v6/v7 pipelining variants all regressed (225/190/195 vs 174).
template <int TAPS, bool RELU, bool HASB, bool FUSE>
static __device__ __forceinline__ void conv_body(
    unsigned short* sIn, unsigned short* sW,
    const unsigned short* __restrict__ inP,
    const unsigned short* __restrict__ wpP,
    const float* __restrict__ biasP,
    unsigned short* __restrict__ outP,
    int n, int r0, int cb,
    const unsigned short* __restrict__ emb,
    float* __restrict__ dout)
{
    constexpr int W_ITERS = TAPS * 4;                       // 36 / 4
    constexpr int SIN_SHORTS = (TAPS == 9) ? 10 * 58 * 32 : 448 * 32;

    const int tid = threadIdx.x;
    const int lane = tid & 63;
    const int wv = tid >> 6;
    const int col = lane & 15;
    const int quad = lane >> 4;

    const unsigned short* inN = inP + (size_t)n * NPIX * 256;
    const unsigned short* wcb = wpP + (size_t)cb * 8 * W_ITERS * 512;

    // per-lane B-frag row offsets (y*58 + x for 3x3; flat px for 1x1)
    int rowoff[7];
#pragma unroll
    for (int nj = 0; nj < 7; nj++) {
        int pxl = wv * 112 + nj * 16 + col;
        if (TAPS == 9) {
            int yl = pxl / 56;
            rowoff[nj] = yl * 58 + (pxl - yl * 56);
        } else {
            rowoff[nj] = pxl;
        }
    }
    const int qoff = quad * 8;
    // per-lane global staging offset within a 16px x 32ci slab
    const int laneSrc = (lane >> 2) * 256 + (lane & 3) * 8;

    if (TAPS == 9) {
        // prezero: x-border pads + out-of-image halo rows stay 0 all chunks
        for (int i = tid * 8; i < SIN_SHORTS; i += 2048)
            *(int4*)(sIn + i) = (int4){0, 0, 0, 0};
    }

    float4v acc[4][7];
#pragma unroll
    for (int mi = 0; mi < 4; mi++)
#pragma unroll
        for (int nj = 0; nj < 7; nj++) acc[mi][nj] = (float4v){0.f, 0.f, 0.f, 0.f};

    for (int ch = 0; ch < 8; ch++) {
        const int c0 = ch * 32;
        __syncthreads();   // prev compute done (first pass: prezero visible)
        // stage weights: contiguous 1KB per wave-iter
        const unsigned short* wchunk = wcb + (size_t)ch * W_ITERS * 512;
#pragma unroll
        for (int it = wv; it < W_ITERS; it += 4)
            async_copy16(wchunk + it * 512 + lane * 8, sW + it * 512);
        // stage input
        if (TAPS == 9) {
#pragma unroll
            for (int ry = 0; ry < 10; ry++) {
                int k = (wv - ry) & 3;          // all (ry,k) covered, balanced
                int gy = r0 + ry - 1;
                if ((unsigned)gy < 56u && (k < 3 || lane < 32))
                    async_copy16(inN + (size_t)gy * 14336 + k * 4096 + c0 + laneSrc,
                                 sIn + ry * 1856 + 32 + k * 512);
            }
        } else {
#pragma unroll
            for (int k = 0; k < 7; k++) {
                int it = wv + k * 4;
                async_copy16(inN + (size_t)r0 * 14336 + it * 4096 + c0 + laneSrc,
                             sIn + it * 512);
            }
        }
        __syncthreads();   // drain + visibility
#pragma unroll
        for (int tap = 0; tap < TAPS; tap++) {
            const int coff = (TAPS == 9) ? ((tap / 3) * 58 + (tap % 3)) * 32 : 0;
            short8v a[4], b[7];
#pragma unroll
            for (int mi = 0; mi < 4; mi++)
                a[mi] = *(const short8v*)(sW + ((tap * 4 + mi) * 64 + lane) * 8);
#pragma unroll
            for (int nj = 0; nj < 7; nj++)
                b[nj] = *(const short8v*)(sIn + rowoff[nj] * 32 + coff + qoff);
#pragma unroll
            for (int mi = 0; mi < 4; mi++)
#pragma unroll
                for (int nj = 0; nj < 7; nj++)
                    acc[mi][nj] = __builtin_amdgcn_mfma_f32_16x16x32_bf16(
                        a[mi], b[nj], acc[mi][nj], 0, 0, 0);
        }
    }

    if (!FUSE) {
        // epilogue: D row = quad*4+reg (cout), col = pixel; no masks
        unsigned short* outT = outP + ((size_t)n * NPIX + r0 * 56 + wv * 112) * 256 + cb * 64;
#pragma unroll
        for (int mi = 0; mi < 4; mi++) {
            float4v bv = (float4v){0.f, 0.f, 0.f, 0.f};
            if (HASB) bv = *(const float4v*)(biasP + cb * 64 + mi * 16 + quad * 4);
#pragma unroll
            for (int nj = 0; nj < 7; nj++) {
                float v0 = acc[mi][nj][0] + bv[0];
                float v1 = acc[mi][nj][1] + bv[1];
                float v2 = acc[mi][nj][2] + bv[2];
                float v3 = acc[mi][nj][3] + bv[3];
                if (RELU) {
                    v0 = fmaxf(v0, 0.f); v1 = fmaxf(v1, 0.f);
                    v2 = fmaxf(v2, 0.f); v3 = fmaxf(v3, 0.f);
                }
                uint2 pk;
                pk.x = (unsigned)f2b(v0) | ((unsigned)f2b(v1) << 16);
                pk.y = (unsigned)f2b(v2) | ((unsigned)f2b(v3) << 16);
                *(uint2*)(outT + ((size_t)(nj * 16 + col)) * 256 + mi * 16 + quad * 4) = pk;
            }
        }
    } else {
        // fused final: p2d = relu(acc+bias) + emb -> fp32 NCHW; pooled atomics
        const int pixBase = r0 * 56 + wv * 112;
        float* p2d = dout + 6144 + (size_t)n * CDIM * NPIX;
        float sums[4][4];
#pragma unroll
        for (int mi = 0; mi < 4; mi++)
#pragma unroll
            for (int q = 0; q < 4; q++) sums[mi][q] = 0.f;
#pragma unroll
        for (int mi = 0; mi < 4; mi++) {
            float4v bv = *(const float4v*)(biasP + cb * 64 + mi * 16 + quad * 4);
            const int co0 = cb * 64 + mi * 16 + quad * 4;
#pragma unroll
            for (int nj = 0; nj < 7; nj++) {
                int pix = pixBase + nj * 16 + col;
                uint2 e = *(const uint2*)(emb + ((size_t)n * NPIX + pix) * 256 + co0);
                float v0 = fmaxf(acc[mi][nj][0] + bv[0], 0.f) + b2f((unsigned short)(e.x & 0xFFFF));
                float v1 = fmaxf(acc[mi][nj][1] + bv[1], 0.f) + b2f((unsigned short)(e.x >> 16));
                float v2 = fmaxf(acc[mi][nj][2] + bv[2], 0.f) + b2f((unsigned short)(e.y & 0xFFFF));
                float v3 = fmaxf(acc[mi][nj][3] + bv[3], 0.f) + b2f((unsigned short)(e.y >> 16));
                p2d[(size_t)(co0 + 0) * NPIX + pix] = v0;
                p2d[(size_t)(co0 + 1) * NPIX + pix] = v1;
                p2d[(size_t)(co0 + 2) * NPIX + pix] = v2;
                p2d[(size_t)(co0 + 3) * NPIX + pix] = v3;
                sums[mi][0] += v0; sums[mi][1] += v1;
                sums[mi][2] += v2; sums[mi][3] += v3;
            }
        }
        // reduce each sum over the 16 lanes of the quad; col==0 lane commits
#pragma unroll
        for (int mi = 0; mi < 4; mi++)
#pragma unroll
            for (int q = 0; q < 4; q++) {
                float s = sums[mi][q];
                s += __shfl_down(s, 8, 16);
                s += __shfl_down(s, 4, 16);
                s += __shfl_down(s, 2, 16);
                s += __shfl_down(s, 1, 16);
                if (col == 0)
                    atomicAdd(dout + n * CDIM + cb * 64 + mi * 16 + quad * 4 + q,
                              s * (1.f / 3136.f));
            }
    }
}

// ---------------- dual-parameter-set conv dispatch --------------------------
// blockIdx.z >= zsplit selects parameter set B (possibly different TAPS /
// relu / bias flags — enables absorbing the short DW conv into E2's idle
// round-2). Wave-uniform branch; LDS sized for the larger (TAPS=9) body.
template <int TA, bool RA, bool HA, int TB, bool RB, bool HB, bool FUSE>
__global__ __launch_bounds__(256, 2) void conv_pair(
    const unsigned short* __restrict__ inA,
    const unsigned short* __restrict__ wpA,
    const float* __restrict__ bA, unsigned short* __restrict__ oA,
    const unsigned short* __restrict__ inB,
    const unsigned short* __restrict__ wpB,
    const float* __restrict__ bB, unsigned short* __restrict__ oB,
    int zsplit,
    const unsigned short* __restrict__ emb,  // (FUSE) bf16 NHWC
    float* __restrict__ dout)                // (FUSE) pooled[6144] + p2d fp32 NCHW
{
    __shared__ unsigned short sIn[10 * 58 * 32];
    __shared__ unsigned short sW[36 * 512];

    const int r0 = blockIdx.x * 8;     // row base; bx==7 is an XCD-pad dummy
    if (r0 >= 56) return;
    int n = blockIdx.z;
    if (n >= zsplit)
        conv_body<TB, RB, HB, FUSE>(sIn, sW, inB, wpB, bB, oB,
                                    n - zsplit, r0, blockIdx.y, emb, dout);
    else
        conv_body<TA, RA, HA, FUSE>(sIn, sW, inA, wpA, bA, oA,
                                    n, r0, blockIdx.y, emb, dout);
}

// ---------------- i_features NCHW fp32 -> NHWC bf16 (fallback only) ---------
__global__ __launch_bounds__(256) void transpose_fI(
    const float* __restrict__ feat, unsigned short* __restrict__ dst)
{
    __shared__ float s[64][65];
    int fi = blockIdx.z;
    int p0 = blockIdx.x * 64;
    int c0 = blockIdx.y * 64;
    int t = threadIdx.x;
    int pl = t & 63, cq = t >> 6;
#pragma unroll
    for (int i = 0; i < 16; i++) {
        int c = cq + i * 4;
        s[pl][c] = feat[((size_t)fi * 256 + c0 + c) * NPIX + p0 + pl];
    }
    __syncthreads();
    int cl = t & 63, pq = t >> 6;
#pragma unroll
    for (int i = 0; i < 16; i++) {
        int p = pq + i * 4;
        dst[((size_t)fi * NPIX + p0 + p) * 256 + c0 + cl] = f2b(s[p][cl]);
    }
}

// ---------------- deform sampling of Z (NHWC bf16) + db ---------------------
__global__ __launch_bounds__(256) void deform_kernel(
    const unsigned short* __restrict__ Z,   // (8,3136,256) bf16
    const float* __restrict__ pm,           // (24,2,3136) fp32
    const float* __restrict__ db,
    unsigned short* __restrict__ out)       // (24,3136,256) bf16
{
    int n = blockIdx.y;
    int t = threadIdx.x;
    int pix = blockIdx.x * 8 + (t >> 5);
    int g = t & 31;                  // 8-channel group
    int fi = n / 3;
    int y = pix / 56, x = pix % 56;
    float dy = pm[((size_t)n * 2 + 0) * NPIX + pix];
    float dx = pm[((size_t)n * 2 + 1) * NPIX + pix];
    float gy = (float)y + dy, gx = (float)x + dx;
    float y0f = floorf(gy), x0f = floorf(gx);
    float ty = gy - y0f, tx = gx - x0f;
    int y0 = (int)y0f, x0 = (int)x0f, y1 = y0 + 1, x1 = x0 + 1;
    bool vy0 = (unsigned)y0 < 56u, vy1 = (unsigned)y1 < 56u;
    bool vx0 = (unsigned)x0 < 56u, vx1 = (unsigned)x1 < 56u;
    float w00 = (1.f - ty) * (1.f - tx) * (vy0 && vx0 ? 1.f : 0.f);
    float w01 = (1.f - ty) * tx * (vy0 && vx1 ? 1.f : 0.f);
    float w10 = ty * (1.f - tx) * (vy1 && vx0 ? 1.f : 0.f);
    float w11 = ty * tx * (vy1 && vx1 ? 1.f : 0.f);
    int y0c = vy0 ? y0 : 0, y1c = vy1 ? y1 : 0;
    int x0c = vx0 ? x0 : 0, x1c = vx1 ? x1 : 0;
    const unsigned short* Zf = Z + (size_t)fi * NPIX * 256 + g * 8;
    const unsigned short* p00 = Zf + (size_t)(y0c * 56 + x0c) * 256;
    const unsigned short* p01 = Zf + (size_t)(y0c * 56 + x1c) * 256;
    const unsigned short* p10 = Zf + (size_t)(y1c * 56 + x0c) * 256;
    const unsigned short* p11 = Zf + (size_t)(y1c * 56 + x1c) * 256;
    unsigned short r[8];
#pragma unroll
    for (int j = 0; j < 8; j++) {
        float v = b2f(p00[j]) * w00 + b2f(p01[j]) * w01 +
                  b2f(p10[j]) * w10 + b2f(p11[j]) * w11;
        v += db[g * 8 + j];
        r[j] = f2b(v);
    }
    *(int4*)(out + ((size_t)n * NPIX + pix) * 256 + g * 8) = *(int4*)r;
}

extern "C" void kernel_launch(void* const* d_in, const int* in_sizes, int n_in,
                              void* d_out, int out_size, void* d_ws, size_t ws_size,
                              hipStream_t stream)
{
    const float* i_features = (const float*)d_in[1];
    const float* p_motions  = (const float*)d_in[2];
    const float* dw  = (const float*)d_in[3];
    const float* db  = (const float*)d_in[4];
    const float* mw1 = (const float*)d_in[5];
    const float* mb1 = (const float*)d_in[6];
    const float* mw2 = (const float*)d_in[7];
    const float* mb2 = (const float*)d_in[8];
    const float* mw3 = (const float*)d_in[9];
    const float* mb3 = (const float*)d_in[10];
    const float* ew1 = (const float*)d_in[11];
    const float* eb1 = (const float*)d_in[12];
    const float* ew2 = (const float*)d_in[13];
    const float* eb2 = (const float*)d_in[14];
    const float* ew3 = (const float*)d_in[15];
    const float* eb3 = (const float*)d_in[16];
    const float* ew4 = (const float*)d_in[17];
    const float* eb4 = (const float*)d_in[18];
    float* out = (float*)d_out;

    // workspace layout (bytes)
    const size_t SZ_PM  = 602112;
    const size_t SZ_WPK = 7208960;
    const size_t SZ_ACT = 38535168;   // 24-frame bf16 NHWC
    char* p = (char*)d_ws;
    float* pm = (float*)p;            p += SZ_PM;
    unsigned short* wpk = (unsigned short*)p;   // 6x 3x3 (contiguous) + 1x1
    unsigned short* wpE2 = wpk + 0 * 589824;
    unsigned short* wpE3 = wpk + 1 * 589824;
    unsigned short* wpE4 = wpk + 2 * 589824;
    unsigned short* wpM1 = wpk + 3 * 589824;
    unsigned short* wpM2 = wpk + 4 * 589824;
    unsigned short* wpM3 = wpk + 5 * 589824;
    unsigned short* wpDW = wpk + 6 * 589824;
    p += SZ_WPK;
    unsigned short* bufA = (unsigned short*)p; p += SZ_ACT;
    unsigned short* bufB = (unsigned short*)p; p += SZ_ACT;
    unsigned short* bufC = (unsigned short*)p; p += SZ_ACT;
    unsigned short* bufD = (unsigned short*)p;     // only used if ws permits

    const bool paired = ws_size >= SZ_PM + SZ_WPK + 4 * SZ_ACT;

    hipMemsetAsync(out, 0, 6144 * sizeof(float), stream);  // pooled accumulators

    resize_pm_kernel<<<(NN * 2 * NPIX + 255) / 256, 256, 0, stream>>>(p_motions, pm);
    pack_all_kernel<<<6 * 2304 + 256, 256, 0, stream>>>(
        ew2, ew3, ew4, mw1, mw2, mw3, dw, wpk);

    const int ewBlocks = 392 * NN;                 // 9408
    dim3 cg48(8, 4, 2 * NN), cgF(8, 4, NN);

    if (paired) {
        // fI lives at bufD[0..8f), Z at bufD[8f..16f) until P1 overwrites D
        unsigned short* fI = bufD;
        unsigned short* Zb = bufD + (size_t)8 * NPIX * 256;
        // merged: ew1 -> A  ||  transpose_fI -> fI
        ew1_fI_kernel<<<ewBlocks + 49 * 4 * 8, 256, 0, stream>>>(
            pm, ew1, eb1, bufA, i_features, fI, ewBlocks);
        // PAIR0: E2 (24f, taps9): A -> B  ||  DW (8f, taps1): fI -> Z
        conv_pair<9, true, true, 1, false, false, false>
            <<<dim3(8, 4, NN + 8), 256, 0, stream>>>(
            bufA, wpE2, eb2, bufB,  fI, wpDW, nullptr, Zb, NN, nullptr, nullptr);
        deform_kernel<<<dim3(392, NN), 256, 0, stream>>>(Zb, pm, db, bufC);
        // P1: E3: B -> A  ||  M1: C -> D   (fI/Z dead by now)
        conv_pair<9, true, true, 9, true, true, false><<<cg48, 256, 0, stream>>>(
            bufB, wpE3, eb3, bufA,  bufC, wpM1, mb1, bufD, NN, nullptr, nullptr);
        // P2: E4: A -> B (emb)  ||  M2: D -> C
        conv_pair<9, true, true, 9, true, true, false><<<cg48, 256, 0, stream>>>(
            bufA, wpE4, eb4, bufB,  bufD, wpM2, mb2, bufC, NN, nullptr, nullptr);
        // final: M3 fused, reads C + emb(B)
        conv_pair<9, true, true, 9, true, true, true><<<cgF, 256, 0, stream>>>(
            bufC, wpM3, mb3, nullptr,  bufC, wpM3, mb3, nullptr, NN, bufB, out);
    } else {
        // fallback: v4 sequence with 3 buffers (A, B, C=emb)
        ew1_fI_kernel<<<ewBlocks, 256, 0, stream>>>(
            pm, ew1, eb1, bufA, nullptr, nullptr, ewBlocks);
        conv_pair<9, true, true, 9, true, true, false><<<cgF, 256, 0, stream>>>(
            bufA, wpE2, eb2, bufB,  bufA, wpE2, eb2, bufB, NN, nullptr, nullptr);
        conv_pair<9, true, true, 9, true, true, false><<<cgF, 256, 0, stream>>>(
            bufB, wpE3, eb3, bufA,  bufB, wpE3, eb3, bufA, NN, nullptr, nullptr);
        conv_pair<9, true, true, 9, true, true, false><<<cgF, 256, 0, stream>>>(
            bufA, wpE4, eb4, bufC,  bufA, wpE4, eb4, bufC, NN, nullptr, nullptr);
        transpose_fI<<<dim3(49, 4, 8), 256, 0, stream>>>(i_features, bufA);
        conv_pair<1, false, false, 1, false, false, false>
            <<<dim3(8, 4, 8), 256, 0, stream>>>(
            bufA, wpDW, nullptr, bufB,  bufA, wpDW, nullptr, bufB, 8, nullptr, nullptr);
        deform_kernel<<<dim3(392, NN), 256, 0, stream>>>(bufB, pm, db, bufA);
        conv_pair<9, true, true, 9, true, true, false><<<cgF, 256, 0, stream>>>(
            bufA, wpM1, mb1, bufB,  bufA, wpM1, mb1, bufB, NN, nullptr, nullptr);
        conv_pair<9, true, true, 9, true, true, false><<<cgF, 256, 0, stream>>>(
            bufB, wpM2, mb2, bufA,  bufB, wpM2, mb2, bufA, NN, nullptr, nullptr);
        conv_pair<9, true, true, 9, true, true, true><<<cgF, 256, 0, stream>>>(
            bufA, wpM3, mb3, nullptr,  bufA, wpM3, mb3, nullptr, NN, bufC, out);
    }
}